// Round 8
// baseline (1689.504 us; speedup 1.0000x reference)
//
#include <hip/hip_runtime.h>
#include <hip/hip_cooperative_groups.h>

namespace cg = cooperative_groups;

// ---------------------------------------------------------------------------
// GCN block, single cooperative kernel (9 grid.sync phases):
//   P0 zero+flag | P1 bucket-hist + GEMM1(unscaled) | P2 scan | P3 scatter |
//   P4 sort(CSR,dinv) | P5 agg1(dinv[src] on gather) | P6 GEMM2 | P7 agg2 |
//   P8 GEMM3 | P9 agg3(+resid, f32 out)
// Rationale: R5-R7 showed ~130us of inter-dispatch gaps dominating; fusing
// to one launch removes them. All inter-stage tensors bf16.
// ---------------------------------------------------------------------------

#define LB 8
#define BKN 256
#define CHUNK 8192

typedef unsigned short ushort_t;
typedef __attribute__((ext_vector_type(8))) short bf16x8;
typedef __attribute__((ext_vector_type(4))) float f32x4;

__device__ __forceinline__ unsigned f2bf(float f) {
    unsigned u = __builtin_bit_cast(unsigned, f);
    return (u + 0x7FFFu + ((u >> 16) & 1u)) >> 16;   // RNE
}
__device__ __forceinline__ float bf2f(ushort_t h) {
    unsigned u = ((unsigned)h) << 16;
    return __builtin_bit_cast(float, u);
}

// per-block int64-vs-int32 probe (sampled; identical result in every block)
__device__ int detect_f64(const int* ei, int E, int* sflag) {
    if (threadIdx.x == 0) *sflag = 0;
    __syncthreads();
    const unsigned* raw = (const unsigned*)ei;
    int dwords = min(2 * E, 4096);
    int any = 0;
    for (int i = threadIdx.x; i < dwords; i += 256)
        if ((i & 1) && raw[i]) any = 1;
    if (any) atomicOr(sflag, 1);
    __syncthreads();
    return !*sflag;   // all sampled high words zero => int64
}

// ---- phase bodies (shared by fused + fallback) ----------------------------
__device__ void hist_dev(const int* ei, int E, int f64, int* bucketCounts,
                         int* sh, int nb) {
    for (int i = threadIdx.x; i < 512; i += 256) sh[i] = 0;
    __syncthreads();
    int stride = nb * 256;
    for (int e = blockIdx.x * 256 + threadIdx.x; e < E; e += stride) {
        int d = f64 ? ei[2 * (E + e)] : ei[E + e];
        atomicAdd(&sh[d >> LB], 1);
    }
    __syncthreads();
    for (int i = threadIdx.x; i < 512; i += 256)
        if (sh[i]) atomicAdd(&bucketCounts[i], sh[i]);
    __syncthreads();
}

__device__ void scan_dev(const int* counts, int* offs, int* cursor, int* ss) {
    int tid = threadIdx.x;
    int v0 = counts[2 * tid], v1 = counts[2 * tid + 1];
    int tsum = v0 + v1;
    ss[tid] = tsum;
    __syncthreads();
    for (int off = 1; off < 256; off <<= 1) {
        int x = (tid >= off) ? ss[tid - off] : 0;
        __syncthreads();
        if (tid >= off) ss[tid] += x;
        __syncthreads();
    }
    int excl = ss[tid] - tsum;
    offs[2 * tid] = excl;
    offs[2 * tid + 1] = excl + v0;
    cursor[2 * tid] = excl;
    cursor[2 * tid + 1] = excl + v0;
    if (tid == 255) offs[512] = ss[255];
}

__device__ void scatter_dev(const int* ei, int E, int f64, int* bucketCursor,
                            unsigned* packed, int c, int* sh, int* sb) {
    int b0 = c * CHUNK;
    int n = min(CHUNK, E - b0);
    for (int i = threadIdx.x; i < 512; i += 256) sh[i] = 0;
    __syncthreads();
    for (int i = threadIdx.x; i < n; i += 256) {
        int e = b0 + i;
        int d = f64 ? ei[2 * (E + e)] : ei[E + e];
        atomicAdd(&sh[d >> LB], 1);
    }
    __syncthreads();
    for (int i = threadIdx.x; i < 512; i += 256) {
        int cc = sh[i];
        sb[i] = cc ? atomicAdd(&bucketCursor[i], cc) : 0;
        sh[i] = 0;
    }
    __syncthreads();
    for (int i = threadIdx.x; i < n; i += 256) {
        int e = b0 + i;
        int d = f64 ? ei[2 * (E + e)] : ei[E + e];
        int s = f64 ? ei[2 * e] : ei[e];
        int bk = d >> LB;
        int pos = sb[bk] + atomicAdd(&sh[bk], 1);
        packed[pos] = ((unsigned)s << LB) | (unsigned)(d & (BKN - 1));
    }
}

__device__ void sort_dev(const unsigned* packed, const int* offs, int* col,
                         int* row_ptr, float* dinv, int N, int E, int b,
                         int* hist, int* ss, int* cur) {
    int tid = threadIdx.x;
    int start = offs[b], end = offs[b + 1];
    hist[tid] = 0;
    __syncthreads();
    for (int e = start + tid; e < end; e += 256)
        atomicAdd(&hist[packed[e] & (BKN - 1)], 1);
    __syncthreads();
    int v = hist[tid];
    ss[tid] = v;
    __syncthreads();
    for (int off = 1; off < 256; off <<= 1) {
        int x = (tid >= off) ? ss[tid - off] : 0;
        __syncthreads();
        if (tid >= off) ss[tid] += x;
        __syncthreads();
    }
    int excl = ss[tid] - v;
    cur[tid] = start + excl;
    int node = (b << LB) + tid;
    if (node < N) {
        row_ptr[node] = start + excl;
        dinv[node] = rsqrtf((float)(v + 1));   // +1 self loop
    }
    if (b == 0 && tid == 0) row_ptr[N] = E;
    __syncthreads();
    for (int e = start + tid; e < end; e += 256) {
        unsigned pv = packed[e];
        int pos = atomicAdd(&cur[pv & (BKN - 1)], 1);
        col[pos] = (int)(pv >> LB);
    }
    __syncthreads();
}

// MFMA GEMM (nrows x K) @ (K x 64) -> bf16 out. Grid-stride over 128-row tiles.
// A frag: A[m=lane&15][k=quad*8+j]; B frag: B[k][n=lane&15];
// C/D: col=lane&15, row=quad*4+reg (learn_hip m89/m91).
template <int K, bool AF32, bool SCALE>
__device__ void gemm_phase(const void* __restrict__ Av, const float* __restrict__ W,
                           const float* __restrict__ dinv, ushort_t* __restrict__ out,
                           int nrows, ushort_t* sWT, int nb) {
    int tid = threadIdx.x;
    int wave = tid >> 6, lane = tid & 63;
    int quad = lane >> 4, l16 = lane & 15;
    int tiles = (nrows + 127) >> 7;
    for (int t = blockIdx.x; t < tiles; t += nb) {
        __syncthreads();
        for (int i = tid; i < K * 64; i += 256) {
            int n = i & 63, k = i >> 6;
            sWT[n * (K + 8) + k] = (ushort_t)f2bf(W[i]);
        }
        __syncthreads();
        int rowBase = t * 128 + wave * 32;
        f32x4 acc[2][4];
#pragma unroll
        for (int r = 0; r < 2; r++)
#pragma unroll
            for (int c = 0; c < 4; c++) acc[r][c] = (f32x4){0.f, 0.f, 0.f, 0.f};
#pragma unroll
        for (int chunk = 0; chunk < K / 32; chunk++) {
            bf16x8 afr[2];
#pragma unroll
            for (int r = 0; r < 2; r++) {
                int row = rowBase + r * 16 + l16;
                if (row >= nrows) row = nrows - 1;
                if (AF32) {
                    const float* ap = (const float*)Av + (size_t)row * K + chunk * 32 + quad * 8;
                    float4 v0 = *(const float4*)ap;
                    float4 v1 = *(const float4*)(ap + 4);
                    bf16x8 a;
                    a[0] = (short)f2bf(v0.x); a[1] = (short)f2bf(v0.y);
                    a[2] = (short)f2bf(v0.z); a[3] = (short)f2bf(v0.w);
                    a[4] = (short)f2bf(v1.x); a[5] = (short)f2bf(v1.y);
                    a[6] = (short)f2bf(v1.z); a[7] = (short)f2bf(v1.w);
                    afr[r] = a;
                } else {
                    const ushort_t* ap = (const ushort_t*)Av + (size_t)row * K + chunk * 32 + quad * 8;
                    afr[r] = __builtin_bit_cast(bf16x8, *(const uint4*)ap);
                }
            }
#pragma unroll
            for (int c = 0; c < 4; c++) {
                bf16x8 bfr = __builtin_bit_cast(
                    bf16x8,
                    *(const uint4*)&sWT[(c * 16 + l16) * (K + 8) + chunk * 32 + quad * 8]);
#pragma unroll
                for (int r = 0; r < 2; r++)
                    acc[r][c] = __builtin_amdgcn_mfma_f32_16x16x32_bf16(
                        afr[r], bfr, acc[r][c], 0, 0, 0);
            }
        }
#pragma unroll
        for (int r = 0; r < 2; r++) {
#pragma unroll
            for (int i = 0; i < 4; i++) {
                int row = rowBase + r * 16 + quad * 4 + i;
                if (row < nrows) {
                    float sc = SCALE ? dinv[row] : 1.0f;
#pragma unroll
                    for (int c = 0; c < 4; c++)
                        out[(size_t)row * 64 + c * 16 + l16] =
                            (ushort_t)f2bf(acc[r][c][i] * sc);
                }
            }
        }
    }
}

// aggregation: one wave per node, lane = feature col, 16-deep gather bursts.
// SSRC: hs is unscaled -> multiply each gathered row by dinv[src].
template <bool SSRC>
__device__ void agg_phase(const ushort_t* __restrict__ hs, const float* __restrict__ dinv,
                          const float* __restrict__ bias, const int* __restrict__ col,
                          const int* __restrict__ row_ptr, const ushort_t* __restrict__ residb,
                          float* __restrict__ outf, ushort_t* __restrict__ outb,
                          int n, int relu, int nb) {
    int lane = threadIdx.x & 63;
    int wavesTotal = nb * 4;
    float bv = bias[lane];
    for (int node = blockIdx.x * 4 + (threadIdx.x >> 6); node < n; node += wavesTotal) {
        int start = row_ptr[node];
        int end = row_ptr[node + 1];
        float dn = dinv[node];
        float acc = bf2f(hs[(size_t)node * 64 + lane]);   // self loop
        if (SSRC) acc *= dn;
        int e = start;
        while (e < end) {
            int cnt = min(64, end - e);
            int myidx = (lane < cnt) ? col[e + lane] : 0;
            int j = 0;
            for (; j + 16 <= cnt; j += 16) {
                int si[16];
                ushort_t u[16];
#pragma unroll
                for (int t = 0; t < 16; t++) si[t] = __shfl(myidx, j + t);
#pragma unroll
                for (int t = 0; t < 16; t++) u[t] = hs[(size_t)si[t] * 64 + lane];
                if (SSRC) {
                    float ds[16];
#pragma unroll
                    for (int t = 0; t < 16; t++) ds[t] = dinv[si[t]];
#pragma unroll
                    for (int t = 0; t < 16; t++) acc += ds[t] * bf2f(u[t]);
                } else {
#pragma unroll
                    for (int t = 0; t < 16; t += 4)
                        acc += bf2f(u[t]) + bf2f(u[t + 1]) + bf2f(u[t + 2]) + bf2f(u[t + 3]);
                }
            }
            for (; j < cnt; j++) {
                int s = __shfl(myidx, j);
                float v = bf2f(hs[(size_t)s * 64 + lane]);
                acc += SSRC ? dinv[s] * v : v;
            }
            e += cnt;
        }
        float o = dn * acc + bv;
        if (relu) o = fmaxf(o, 0.f);
        if (residb) o += bf2f(residb[(size_t)node * 64 + lane]);
        if (outf) outf[(size_t)node * 64 + lane] = o;
        if (outb) outb[(size_t)node * 64 + lane] = (ushort_t)f2bf(o);
    }
}

// ---- fused cooperative kernel ---------------------------------------------
struct Params {
    const float* x; const int* ei;
    const float* W0; const float* b0; const float* Ws; const float* bs;
    float* out;
    int N, E, B;
    int* bucketCounts; int* bucketOffs; int* bucketCursor;
    unsigned* packed; int* col; int* row_ptr; float* dinv;
    ushort_t* hs; ushort_t* xtb; ushort_t* hb;
};

union Smem {
    ushort_t wt[64 * 136];                                  // GEMM W^T (K<=128)
    struct { int hist[512]; int base[512]; } sc;            // hist/scatter
    struct { int hist[256]; int s[256]; int cur[256]; } srt;// sort
    struct { int s[256]; } scan;                            // scan
};

__global__ __launch_bounds__(256, 4) void fused_kernel(Params p) {
    cg::grid_group grid = cg::this_grid();
    __shared__ Smem sm;
    __shared__ int sflag;
    int nb = gridDim.x;

    // P0: flag (per-block register) + zero bucketCounts
    int f64 = detect_f64(p.ei, p.E, &sflag);
    if (blockIdx.x == 0)
        for (int i = threadIdx.x; i < 512; i += 256) p.bucketCounts[i] = 0;
    __threadfence();
    grid.sync();

    // P1: bucket hist + GEMM1 (unscaled; dinv not ready yet)
    hist_dev(p.ei, p.E, f64, p.bucketCounts, sm.sc.hist, nb);
    gemm_phase<128, true, false>(p.x, p.W0, p.dinv, p.hs, p.N, sm.wt, nb);
    __threadfence();
    grid.sync();

    // P2: bucket scan (block 0)
    if (blockIdx.x == 0)
        scan_dev(p.bucketCounts, p.bucketOffs, p.bucketCursor, sm.scan.s);
    __threadfence();
    grid.sync();

    // P3: scatter to packed
    {
        int nchunks = (p.E + CHUNK - 1) / CHUNK;
        for (int c = blockIdx.x; c < nchunks; c += nb) {
            __syncthreads();
            scatter_dev(p.ei, p.E, f64, p.bucketCursor, p.packed, c,
                        sm.sc.hist, sm.sc.base);
        }
    }
    __threadfence();
    grid.sync();

    // P4: per-bucket sort -> col, row_ptr, dinv
    for (int b = blockIdx.x; b < p.B; b += nb) {
        __syncthreads();
        sort_dev(p.packed, p.bucketOffs, p.col, p.row_ptr, p.dinv, p.N, p.E, b,
                 sm.srt.hist, sm.srt.s, sm.srt.cur);
    }
    __threadfence();
    grid.sync();

    // P5: agg1 (dinv[src] on gather) -> xtb
    agg_phase<true>(p.hs, p.dinv, p.b0, p.col, p.row_ptr, nullptr,
                    nullptr, p.xtb, p.N, 0, nb);
    __threadfence();
    grid.sync();

    // P6: GEMM2
    gemm_phase<64, false, true>(p.xtb, p.Ws, p.dinv, p.hs, p.N, sm.wt, nb);
    __threadfence();
    grid.sync();

    // P7: agg2 -> hb (relu)
    agg_phase<false>(p.hs, p.dinv, p.bs, p.col, p.row_ptr, nullptr,
                     nullptr, p.hb, p.N, 1, nb);
    __threadfence();
    grid.sync();

    // P8: GEMM3
    gemm_phase<64, false, true>(p.hb, p.Ws + 64 * 64, p.dinv, p.hs, p.N, sm.wt, nb);
    __threadfence();
    grid.sync();

    // P9: agg3 -> out (f32, relu, +resid)
    agg_phase<false>(p.hs, p.dinv, p.bs + 64, p.col, p.row_ptr, p.xtb,
                     p.out, nullptr, p.N, 1, nb);
}

// ---- fallback (non-cooperative) kernels -----------------------------------
__global__ __launch_bounds__(256) void k_hist(const int* ei, int E, int* bc) {
    __shared__ int sh[512];
    __shared__ int sflag;
    int f64 = detect_f64(ei, E, &sflag);
    hist_dev(ei, E, f64, bc, sh, gridDim.x);
}
__global__ __launch_bounds__(256) void k_scan(const int* counts, int* offs, int* cursor) {
    __shared__ int ss[256];
    scan_dev(counts, offs, cursor, ss);
}
__global__ __launch_bounds__(256) void k_scatter(const int* ei, int E, int* cursor,
                                                 unsigned* packed) {
    __shared__ int sh[512];
    __shared__ int sb[512];
    __shared__ int sflag;
    int f64 = detect_f64(ei, E, &sflag);
    int nchunks = (E + CHUNK - 1) / CHUNK;
    for (int c = blockIdx.x; c < nchunks; c += gridDim.x) {
        __syncthreads();
        scatter_dev(ei, E, f64, cursor, packed, c, sh, sb);
    }
}
__global__ __launch_bounds__(256) void k_sort(const unsigned* packed, const int* offs,
                                              int* col, int* row_ptr, float* dinv,
                                              int N, int E) {
    __shared__ int hist[256], ss[256], cur[256];
    for (int b = blockIdx.x; b < ((N + BKN - 1) >> LB); b += gridDim.x) {
        __syncthreads();
        sort_dev(packed, offs, col, row_ptr, dinv, N, E, b, hist, ss, cur);
    }
}
template <int K, bool AF32, bool SCALE>
__global__ __launch_bounds__(256) void k_gemm(const void* Av, const float* W,
                                              const float* dinv, ushort_t* out, int n) {
    __shared__ ushort_t swt[64 * 136];
    gemm_phase<K, AF32, SCALE>(Av, W, dinv, out, n, swt, gridDim.x);
}
template <bool SSRC>
__global__ __launch_bounds__(256) void k_agg(const ushort_t* hs, const float* dinv,
                                             const float* bias, const int* col,
                                             const int* row_ptr, const ushort_t* residb,
                                             float* outf, ushort_t* outb, int n, int relu) {
    agg_phase<SSRC>(hs, dinv, bias, col, row_ptr, residb, outf, outb, n, relu, gridDim.x);
}

// ---------------------------------------------------------------------------
extern "C" void kernel_launch(void* const* d_in, const int* in_sizes, int n_in,
                              void* d_out, int out_size, void* d_ws, size_t ws_size,
                              hipStream_t stream) {
    const float* x  = (const float*)d_in[0];
    const int*   ei = (const int*)d_in[1];
    const float* W0 = (const float*)d_in[2];
    const float* b0 = (const float*)d_in[3];
    const float* Ws = (const float*)d_in[4];
    const float* bs = (const float*)d_in[5];
    float* out = (float*)d_out;

    const int N = in_sizes[0] / 128;
    const int E = in_sizes[1] / 2;
    const int B = (N + BKN - 1) >> LB;

    char* p = (char*)d_ws;
    auto carve = [&](size_t bytes) {
        char* r = p;
        p += (bytes + 255) & ~(size_t)255;
        return r;
    };
    int*      bucketCounts = (int*)carve(512 * 4);
    int*      bucketOffs   = (int*)carve(513 * 4);
    int*      bucketCursor = (int*)carve(512 * 4);
    unsigned* packed       = (unsigned*)carve((size_t)E * 4);
    int*      col          = (int*)carve((size_t)E * 4);
    int*      row_ptr      = (int*)carve((size_t)(N + 1) * 4);
    float*    dinv         = (float*)carve((size_t)N * 4);
    ushort_t* hs           = (ushort_t*)carve((size_t)N * 64 * 2);
    ushort_t* xtb          = (ushort_t*)carve((size_t)N * 64 * 2);
    ushort_t* hb           = (ushort_t*)carve((size_t)N * 64 * 2);

    Params prm;
    prm.x = x; prm.ei = ei; prm.W0 = W0; prm.b0 = b0; prm.Ws = Ws; prm.bs = bs;
    prm.out = out; prm.N = N; prm.E = E; prm.B = B;
    prm.bucketCounts = bucketCounts; prm.bucketOffs = bucketOffs;
    prm.bucketCursor = bucketCursor; prm.packed = packed; prm.col = col;
    prm.row_ptr = row_ptr; prm.dinv = dinv; prm.hs = hs; prm.xtb = xtb; prm.hb = hb;

    int maxBpc = 0;
    hipError_t oe = hipOccupancyMaxActiveBlocksPerMultiprocessor(&maxBpc, fused_kernel, 256, 0);
    if (oe == hipSuccess && maxBpc >= 1) {
        int grid = maxBpc * 256;          // 256 CUs on MI355X
        if (grid > 2048) grid = 2048;
        void* args[] = { &prm };
        hipError_t le = hipLaunchCooperativeKernel((void*)fused_kernel, dim3(grid),
                                                   dim3(256), args, 0, stream);
        if (le == hipSuccess) return;
    }

    // -------- fallback: non-cooperative multi-launch path --------
    hipMemsetAsync(bucketCounts, 0, 512 * 4, stream);
    k_hist<<<512, 256, 0, stream>>>(ei, E, bucketCounts);
    k_scan<<<1, 256, 0, stream>>>(bucketCounts, bucketOffs, bucketCursor);
    k_scatter<<<(E + CHUNK - 1) / CHUNK, 256, 0, stream>>>(ei, E, bucketCursor, packed);
    k_sort<<<B, 256, 0, stream>>>(packed, bucketOffs, col, row_ptr, dinv, N, E);
    int gblocks = (N + 127) / 128;
    int ablocks = (N + 3) / 4;
    k_gemm<128, true, false><<<gblocks, 256, 0, stream>>>(x, W0, dinv, hs, N);
    k_agg<true><<<ablocks, 256, 0, stream>>>(hs, dinv, b0, col, row_ptr,
                                             nullptr, nullptr, xtb, N, 0);
    k_gemm<64, false, true><<<gblocks, 256, 0, stream>>>(xtb, Ws, dinv, hs, N);
    k_agg<false><<<ablocks, 256, 0, stream>>>(hs, dinv, bs, col, row_ptr,
                                              nullptr, nullptr, hb, N, 1);
    k_gemm<64, false, true><<<gblocks, 256, 0, stream>>>(hb, Ws + 64 * 64, dinv, hs, N);
    k_agg<false><<<ablocks, 256, 0, stream>>>(hs, dinv, bs + 64, col, row_ptr,
                                              xtb, out, nullptr, N, 1);
}

// Round 9
// 444.435 us; speedup vs baseline: 3.8015x; 3.8015x over previous
//
#include <hip/hip_runtime.h>

// ---------------------------------------------------------------------------
// GCN block: 3x (MFMA bf16 GEMM -> degree-normalized aggregate), resid, relu.
// Multi-launch (R7 structure) with a shortened dependent chain (9 dispatches):
//   memset | k1 = [GEMM1(unscaled) || bucket-hist + last-block scan] |
//   scatter | sort | agg1(dinv[src] per gather) | gemm2 | agg2 | gemm3 | agg3
// R8 lesson: cooperative phase-fusion caps TLP at resident-grid size and
// wrecked the latency-bound gather (24% occ, 5% VALU). Oversubscribed
// per-stage grids (25k-block aggregates) are what hide gather latency.
// All inter-stage tensors bf16; f32 only for the final output.
// ---------------------------------------------------------------------------

#define LB 8
#define BKN 256
#define CHUNK 8192

typedef unsigned short ushort_t;
typedef __attribute__((ext_vector_type(8))) short bf16x8;
typedef __attribute__((ext_vector_type(4))) float f32x4;

__device__ __forceinline__ unsigned f2bf(float f) {
    unsigned u = __builtin_bit_cast(unsigned, f);
    return (u + 0x7FFFu + ((u >> 16) & 1u)) >> 16;   // RNE
}
__device__ __forceinline__ float bf2f(ushort_t h) {
    unsigned u = ((unsigned)h) << 16;
    return __builtin_bit_cast(float, u);
}

// per-block int64-vs-int32 probe (sampled; same result in every block)
__device__ int detect_f64(const int* ei, int E, int* sflag) {
    if (threadIdx.x == 0) *sflag = 0;
    __syncthreads();
    const unsigned* raw = (const unsigned*)ei;
    int dwords = min(2 * E, 4096);
    int any = 0;
    for (int i = threadIdx.x; i < dwords; i += 256)
        if ((i & 1) && raw[i]) any = 1;
    if (any) atomicOr(sflag, 1);
    __syncthreads();
    return !*sflag;   // all sampled high words zero => int64
}

// ---- k1: GEMM1 (blocks < gb) || bucket hist + fused scan (blocks >= gb) ---
__global__ __launch_bounds__(256) void k1_gemm_hist(
        const float* __restrict__ x, const float* __restrict__ W0,
        ushort_t* __restrict__ hs, int N,
        const int* __restrict__ ei, int E,
        int* __restrict__ bucketCounts, int* __restrict__ done,
        int* __restrict__ offs, int* __restrict__ cursor, int gb) {
    __shared__ union {
        ushort_t wt[64 * 136];
        struct { int h[512]; int flag; int last; } hh;
    } sm;
    int tid = threadIdx.x;

    if ((int)blockIdx.x < gb) {
        // ---------------- GEMM1: (N x 128) @ (128 x 64), unscaled bf16 out
        const int K = 128;
        for (int i = tid; i < K * 64; i += 256) {
            int n = i & 63, k = i >> 6;
            sm.wt[n * (K + 8) + k] = (ushort_t)f2bf(W0[i]);
        }
        __syncthreads();
        int wave = tid >> 6, lane = tid & 63;
        int quad = lane >> 4, l16 = lane & 15;
        int rowBase = blockIdx.x * 128 + wave * 32;
        f32x4 acc[2][4];
#pragma unroll
        for (int r = 0; r < 2; r++)
#pragma unroll
            for (int c = 0; c < 4; c++) acc[r][c] = (f32x4){0.f, 0.f, 0.f, 0.f};
#pragma unroll
        for (int chunk = 0; chunk < K / 32; chunk++) {
            bf16x8 afr[2];
#pragma unroll
            for (int r = 0; r < 2; r++) {
                int row = rowBase + r * 16 + l16;
                if (row >= N) row = N - 1;
                const float* ap = x + (size_t)row * K + chunk * 32 + quad * 8;
                float4 v0 = *(const float4*)ap;
                float4 v1 = *(const float4*)(ap + 4);
                bf16x8 a;
                a[0] = (short)f2bf(v0.x); a[1] = (short)f2bf(v0.y);
                a[2] = (short)f2bf(v0.z); a[3] = (short)f2bf(v0.w);
                a[4] = (short)f2bf(v1.x); a[5] = (short)f2bf(v1.y);
                a[6] = (short)f2bf(v1.z); a[7] = (short)f2bf(v1.w);
                afr[r] = a;
            }
#pragma unroll
            for (int c = 0; c < 4; c++) {
                bf16x8 bfr = __builtin_bit_cast(
                    bf16x8,
                    *(const uint4*)&sm.wt[(c * 16 + l16) * (K + 8) + chunk * 32 + quad * 8]);
#pragma unroll
                for (int r = 0; r < 2; r++)
                    acc[r][c] = __builtin_amdgcn_mfma_f32_16x16x32_bf16(
                        afr[r], bfr, acc[r][c], 0, 0, 0);
            }
        }
#pragma unroll
        for (int r = 0; r < 2; r++)
#pragma unroll
            for (int i = 0; i < 4; i++) {
                int row = rowBase + r * 16 + quad * 4 + i;
                if (row < N)
#pragma unroll
                    for (int c = 0; c < 4; c++)
                        hs[(size_t)row * 64 + c * 16 + l16] =
                            (ushort_t)f2bf(acc[r][c][i]);
            }
        return;
    }

    // ---------------- hist (512 blocks) + last-block scan
    int hb = blockIdx.x - gb;          // 0..511
    int f64 = detect_f64(ei, E, &sm.hh.flag);
    for (int i = tid; i < 512; i += 256) sm.hh.h[i] = 0;
    __syncthreads();
    int stride = 512 * 256;
    for (int e = hb * 256 + tid; e < E; e += stride) {
        int d = f64 ? ei[2 * (E + e)] : ei[E + e];
        atomicAdd(&sm.hh.h[d >> LB], 1);
    }
    __syncthreads();
    for (int i = tid; i < 512; i += 256)
        if (sm.hh.h[i]) atomicAdd(&bucketCounts[i], sm.hh.h[i]);
    __threadfence();
    if (tid == 0) sm.hh.last = (atomicAdd(done, 1) == 511);
    __syncthreads();
    if (!sm.hh.last) return;
    __threadfence();
    // exclusive scan of 512 bucket counts with 256 threads
    int v0 = bucketCounts[2 * tid];
    int v1 = bucketCounts[2 * tid + 1];
    int tsum = v0 + v1;
    sm.hh.h[tid] = tsum;
    __syncthreads();
    for (int off = 1; off < 256; off <<= 1) {
        int xw = (tid >= off) ? sm.hh.h[tid - off] : 0;
        __syncthreads();
        if (tid >= off) sm.hh.h[tid] += xw;
        __syncthreads();
    }
    int excl = sm.hh.h[tid] - tsum;
    offs[2 * tid] = excl;
    offs[2 * tid + 1] = excl + v0;
    cursor[2 * tid] = excl;
    cursor[2 * tid + 1] = excl + v0;
    if (tid == 255) offs[512] = sm.hh.h[255];
}

// ---- scatter: partition edges as packed (src<<8 | dst&255) ----------------
__global__ __launch_bounds__(256) void k_scatter(
        const int* __restrict__ ei, int E,
        int* __restrict__ bucketCursor, unsigned int* __restrict__ packed) {
    __shared__ int hist[512];
    __shared__ int base[512];
    __shared__ int sflag;
    int f64 = detect_f64(ei, E, &sflag);
    int b0 = blockIdx.x * CHUNK;
    int n = min(CHUNK, E - b0);
    for (int i = threadIdx.x; i < 512; i += 256) hist[i] = 0;
    __syncthreads();
    for (int i = threadIdx.x; i < n; i += 256) {
        int e = b0 + i;
        int d = f64 ? ei[2 * (E + e)] : ei[E + e];
        atomicAdd(&hist[d >> LB], 1);
    }
    __syncthreads();
    for (int i = threadIdx.x; i < 512; i += 256) {
        int c = hist[i];
        base[i] = c ? atomicAdd(&bucketCursor[i], c) : 0;
        hist[i] = 0;
    }
    __syncthreads();
    for (int i = threadIdx.x; i < n; i += 256) {
        int e = b0 + i;
        int d = f64 ? ei[2 * (E + e)] : ei[E + e];
        int s = f64 ? ei[2 * e] : ei[e];
        int bk = d >> LB;
        int pos = base[bk] + atomicAdd(&hist[bk], 1);
        packed[pos] = ((unsigned)s << LB) | (unsigned)(d & (BKN - 1));
    }
}

// ---- per-bucket counting sort: packed -> CSR col[], row_ptr, dinv ---------
__global__ __launch_bounds__(256) void k_sort(
        const unsigned int* __restrict__ packed, const int* __restrict__ offs,
        int* __restrict__ col, int* __restrict__ row_ptr, float* __restrict__ dinv,
        int N, int E) {
    __shared__ int hist[BKN];
    __shared__ int s[BKN];
    __shared__ int cur[BKN];
    int tid = threadIdx.x;
    int b = blockIdx.x;
    int start = offs[b], end = offs[b + 1];
    hist[tid] = 0;
    __syncthreads();
    for (int e = start + tid; e < end; e += 256)
        atomicAdd(&hist[packed[e] & (BKN - 1)], 1);
    __syncthreads();
    int v = hist[tid];
    s[tid] = v;
    __syncthreads();
    for (int off = 1; off < 256; off <<= 1) {
        int x = (tid >= off) ? s[tid - off] : 0;
        __syncthreads();
        if (tid >= off) s[tid] += x;
        __syncthreads();
    }
    int excl = s[tid] - v;
    cur[tid] = start + excl;
    int node = (b << LB) + tid;
    if (node < N) {
        row_ptr[node] = start + excl;
        dinv[node] = rsqrtf((float)(v + 1));   // +1 self loop
    }
    if (b == 0 && tid == 0) row_ptr[N] = E;
    __syncthreads();
    for (int e = start + tid; e < end; e += 256) {
        unsigned pv = packed[e];
        int pos = atomicAdd(&cur[pv & (BKN - 1)], 1);
        col[pos] = (int)(pv >> LB);
    }
}

// ---- MFMA GEMM (N x 64) @ (64 x 64), epilogue dinv-scale, bf16 out --------
__global__ __launch_bounds__(256) void k_gemm64(
        const ushort_t* __restrict__ A, const float* __restrict__ W,
        const float* __restrict__ dinv, ushort_t* __restrict__ out, int nrows) {
    const int K = 64;
    __shared__ ushort_t sWT[64 * (K + 8)];
    int tid = threadIdx.x;
    for (int i = tid; i < K * 64; i += 256) {
        int n = i & 63, k = i >> 6;
        sWT[n * (K + 8) + k] = (ushort_t)f2bf(W[i]);
    }
    __syncthreads();
    int wave = tid >> 6, lane = tid & 63;
    int quad = lane >> 4, l16 = lane & 15;
    int rowBase = blockIdx.x * 128 + wave * 32;
    f32x4 acc[2][4];
#pragma unroll
    for (int r = 0; r < 2; r++)
#pragma unroll
        for (int c = 0; c < 4; c++) acc[r][c] = (f32x4){0.f, 0.f, 0.f, 0.f};
#pragma unroll
    for (int chunk = 0; chunk < K / 32; chunk++) {
        bf16x8 afr[2];
#pragma unroll
        for (int r = 0; r < 2; r++) {
            int row = rowBase + r * 16 + l16;
            if (row >= nrows) row = nrows - 1;
            const ushort_t* ap = A + (size_t)row * K + chunk * 32 + quad * 8;
            afr[r] = __builtin_bit_cast(bf16x8, *(const uint4*)ap);
        }
#pragma unroll
        for (int c = 0; c < 4; c++) {
            bf16x8 bfr = __builtin_bit_cast(
                bf16x8,
                *(const uint4*)&sWT[(c * 16 + l16) * (K + 8) + chunk * 32 + quad * 8]);
#pragma unroll
            for (int r = 0; r < 2; r++)
                acc[r][c] = __builtin_amdgcn_mfma_f32_16x16x32_bf16(
                    afr[r], bfr, acc[r][c], 0, 0, 0);
        }
    }
#pragma unroll
    for (int r = 0; r < 2; r++)
#pragma unroll
        for (int i = 0; i < 4; i++) {
            int row = rowBase + r * 16 + quad * 4 + i;
            if (row < nrows) {
                float sc = dinv[row];
#pragma unroll
                for (int c = 0; c < 4; c++)
                    out[(size_t)row * 64 + c * 16 + l16] =
                        (ushort_t)f2bf(acc[r][c][i] * sc);
            }
        }
}

// ---- aggregation: one wave per node, lane = feature column ----------------
// SSRC: hs unscaled -> multiply each gathered row (and self) by dinv[·].
template <bool SSRC>
__global__ __launch_bounds__(256) void k_agg(
        const ushort_t* __restrict__ hs, const float* __restrict__ dinv,
        const float* __restrict__ bias, const int* __restrict__ col,
        const int* __restrict__ row_ptr, const ushort_t* __restrict__ residb,
        float* __restrict__ outf, ushort_t* __restrict__ outb, int n, int relu) {
    int node = (blockIdx.x * blockDim.x + threadIdx.x) >> 6;
    int lane = threadIdx.x & 63;
    if (node >= n) return;
    int start = row_ptr[node];
    int end = row_ptr[node + 1];
    float dn = dinv[node];
    float acc = bf2f(hs[(size_t)node * 64 + lane]);   // self loop
    if (SSRC) acc *= dn;
    int e = start;
    while (e < end) {
        int cnt = min(64, end - e);
        int myidx = (lane < cnt) ? col[e + lane] : 0;
        int j = 0;
        for (; j + 16 <= cnt; j += 16) {
            int si[16];
            ushort_t u[16];
#pragma unroll
            for (int t = 0; t < 16; t++) si[t] = __shfl(myidx, j + t);
#pragma unroll
            for (int t = 0; t < 16; t++) u[t] = hs[(size_t)si[t] * 64 + lane];
            if (SSRC) {
                float ds[16];
#pragma unroll
                for (int t = 0; t < 16; t++) ds[t] = dinv[si[t]];
#pragma unroll
                for (int t = 0; t < 16; t++) acc += ds[t] * bf2f(u[t]);
            } else {
#pragma unroll
                for (int t = 0; t < 16; t += 4)
                    acc += bf2f(u[t]) + bf2f(u[t + 1]) + bf2f(u[t + 2]) + bf2f(u[t + 3]);
            }
        }
        for (; j < cnt; j++) {
            int s = __shfl(myidx, j);
            float v = bf2f(hs[(size_t)s * 64 + lane]);
            acc += SSRC ? dinv[s] * v : v;
        }
        e += cnt;
    }
    float o = dn * acc + bias[lane];
    if (relu) o = fmaxf(o, 0.f);
    if (residb) o += bf2f(residb[(size_t)node * 64 + lane]);
    if (outf) outf[(size_t)node * 64 + lane] = o;
    if (outb) outb[(size_t)node * 64 + lane] = (ushort_t)f2bf(o);
}

// ---------------------------------------------------------------------------
extern "C" void kernel_launch(void* const* d_in, const int* in_sizes, int n_in,
                              void* d_out, int out_size, void* d_ws, size_t ws_size,
                              hipStream_t stream) {
    const float* x  = (const float*)d_in[0];
    const int*   ei = (const int*)d_in[1];
    const float* W0 = (const float*)d_in[2];
    const float* b0 = (const float*)d_in[3];
    const float* Ws = (const float*)d_in[4];
    const float* bs = (const float*)d_in[5];
    float* out = (float*)d_out;

    const int N = in_sizes[0] / 128;
    const int E = in_sizes[1] / 2;
    const int B = (N + BKN - 1) >> LB;

    char* p = (char*)d_ws;
    auto carve = [&](size_t bytes) {
        char* r = p;
        p += (bytes + 255) & ~(size_t)255;
        return r;
    };
    int*      zeroed       = (int*)carve((512 + 1) * 4);
    int*      bucketCounts = zeroed;
    int*      done         = zeroed + 512;
    int*      bucketOffs   = (int*)carve(513 * 4);
    int*      bucketCursor = (int*)carve(512 * 4);
    unsigned* packed       = (unsigned*)carve((size_t)E * 4);
    int*      col          = (int*)carve((size_t)E * 4);
    int*      row_ptr      = (int*)carve((size_t)(N + 1) * 4);
    float*    dinv         = (float*)carve((size_t)N * 4);
    ushort_t* hs           = (ushort_t*)carve((size_t)N * 64 * 2);
    ushort_t* xtb          = (ushort_t*)carve((size_t)N * 64 * 2);
    ushort_t* hb           = (ushort_t*)carve((size_t)N * 64 * 2);

    hipMemsetAsync(zeroed, 0, (512 + 1) * 4, stream);

    int gb = (N + 127) / 128;                 // 782 GEMM tiles
    int ablocks = (N + 3) / 4;                // 25k blocks, wave-per-node

    // k1: GEMM1 (unscaled) || hist+scan
    k1_gemm_hist<<<gb + 512, 256, 0, stream>>>(
        x, W0, hs, N, ei, E, bucketCounts, done, bucketOffs, bucketCursor, gb);
    k_scatter<<<(E + CHUNK - 1) / CHUNK, 256, 0, stream>>>(ei, E, bucketCursor, packed);
    k_sort<<<B, 256, 0, stream>>>(packed, bucketOffs, col, row_ptr, dinv, N, E);

    // layer 1: x_temp = agg(x @ W0 * dinv_src) + b0   (bf16 out)
    k_agg<true><<<ablocks, 256, 0, stream>>>(hs, dinv, b0, col, row_ptr,
                                             nullptr, nullptr, xtb, N, 0);
    // layer 2
    k_gemm64<<<gb, 256, 0, stream>>>(xtb, Ws, dinv, hs, N);
    k_agg<false><<<ablocks, 256, 0, stream>>>(hs, dinv, bs, col, row_ptr,
                                              nullptr, nullptr, hb, N, 1);
    // layer 3
    k_gemm64<<<gb, 256, 0, stream>>>(hb, Ws + 64 * 64, dinv, hs, N);
    k_agg<false><<<ablocks, 256, 0, stream>>>(hs, dinv, bs + 64, col, row_ptr,
                                              xtb, out, nullptr, N, 1);
}